// Round 8
// baseline (497.306 us; speedup 1.0000x reference)
//
#include <hip/hip_runtime.h>
#include <hip/hip_bf16.h>

// LightGCN: 3 layers of SpMM on 200000x64 embeddings, 3.2M edges.
// R12: capacity attack on gather L2-miss (the only remaining lever; R11
//      proved timing/ordering is not one). (a) Dim-split: SpMM is
//      per-dimension independent -> run each layer as TWO launches over
//      32-dim halves (64B rows = one sector). Gather table per launch =
//      12.8MB (2x per-XCD L2 coverage); launch boundaries force all
//      blocks onto the same half (no block drift); halves chained
//      L0h0,L1h0,L2h0,L0h1.. so the hot half persists. (b) 4B records:
//      sorted = u32 col(18)|wfix14 (abs err 3e-5, negligible vs bf16) -
//      cancels the 2x sorted re-read and halves sort_bucket write.
//      R11 slice key reverted (measured neutral). bin_edges frozen.
// R10: spmm LDS record staging + 8-deep gather MLP.
// R9:  bin_edges block-local counting sort + coalesced run flush.
// R7:  no f32 acc RMW (layer2 fuses out=(a+y1+y2)/3).
// R5:  two-level counting-sort CSR build.

constexpr int NUM_USERS = 100000;
constexpr int NUM_ITEMS = 100000;
constexpr int N_NODES   = NUM_USERS + NUM_ITEMS;   // 200000
constexpr int EMB       = 64;
constexpr int N_EDGES   = 3200000;

constexpr int BUCK_SHIFT = 8;                       // 256 rows per bucket
constexpr int NBUCK = (N_NODES + 255) >> BUCK_SHIFT; // 782
constexpr int BIN_BLOCK = 512;
constexpr int EPB = 8192;                            // edges per bin block
constexpr int NBIN_BLOCKS = (N_EDGES + EPB - 1) / EPB; // 391
constexpr int SORT_CAP = 6144;                       // mean 4096, sigma 64

constexpr int HIST_BLOCKS   = 512;
constexpr int CONCAT_BLOCKS = (N_NODES * 8 + 255) / 256; // 6250

constexpr int SROWS = 64;                            // spmm rows per block
constexpr int ECAP  = 2560;                          // LDS record cap (mean 1024)

// ---------------- bf16 helpers ----------------

__device__ __forceinline__ float bfl(unsigned u) { return __uint_as_float(u << 16); }
__device__ __forceinline__ float bfh(unsigned u) { return __uint_as_float(u & 0xFFFF0000u); }
__device__ __forceinline__ unsigned f2bf(float f) {          // RNE
    unsigned u = __float_as_uint(f);
    return (u + 0x7FFFu + ((u >> 16) & 1u)) >> 16;
}
__device__ __forceinline__ unsigned pk(float lo, float hi) {
    return f2bf(lo) | (f2bf(hi) << 16);
}

// ---------------- prep: coarse histogram + concat->bf16 half-layout ----------------
// ebuf layout: [half][node][4 x uint4]  (64B half-rows, dims h*32..h*32+31)

__global__ __launch_bounds__(256) void prep(
    const int* __restrict__ row, int* __restrict__ bcnt,
    const float4* __restrict__ u, const float4* __restrict__ it,
    uint4* __restrict__ ebuf) {
    __shared__ int h[NBUCK];
    if (blockIdx.x < HIST_BLOCKS) {
        for (int i = threadIdx.x; i < NBUCK; i += 256) h[i] = 0;
        __syncthreads();
        int nt = HIST_BLOCKS * 256;
        for (int e = blockIdx.x * 256 + threadIdx.x; e < N_EDGES; e += nt) {
            int r = __builtin_nontemporal_load(&row[e]);
            atomicAdd(&h[r >> BUCK_SHIFT], 1);
        }
        __syncthreads();
        for (int i = threadIdx.x; i < NBUCK; i += 256) {
            int c = h[i];
            if (c) atomicAdd(&bcnt[i], c);
        }
    } else {
        int j = (blockIdx.x - HIST_BLOCKS) * 256 + threadIdx.x;  // out uint4 idx
        if (j >= N_NODES * 8) return;
        int hf   = (j >= N_NODES * 4) ? 1 : 0;
        int idx  = j - hf * N_NODES * 4;
        int node = idx >> 2;
        int s    = idx & 3;
        const float4* sp = (node < NUM_USERS)
            ? (u  + (size_t)node * 16 + hf * 8 + s * 2)
            : (it + (size_t)(node - NUM_USERS) * 16 + hf * 8 + s * 2);
        float4 f0 = sp[0], f1 = sp[1];
        uint4 o;
        o.x = pk(f0.x, f0.y); o.y = pk(f0.z, f0.w);
        o.z = pk(f1.x, f1.y); o.w = pk(f1.z, f1.w);
        ebuf[j] = o;
    }
}

// ---------------- CSR build: two-level counting sort ----------------

// Exclusive scan of 782 bucket counts -> bucket bases + cursors.
__global__ __launch_bounds__(1024) void scan_buckets(const int* __restrict__ bcnt,
                                                     int* __restrict__ bbase,
                                                     int* __restrict__ bcursor) {
    __shared__ int lds[1024];
    int t = threadIdx.x;
    int v = (t < NBUCK) ? bcnt[t] : 0;
    lds[t] = v;
    __syncthreads();
    for (int off = 1; off < 1024; off <<= 1) {
        int x = (t >= off) ? lds[t - off] : 0;
        __syncthreads();
        lds[t] += x;
        __syncthreads();
    }
    int excl = lds[t] - v;
    if (t < NBUCK) { bbase[t] = excl; bcursor[t] = excl; }
    if (t == 0) bbase[NBUCK] = N_EDGES;
}

// Bin edges into coarse buckets, block-local counting sort in LDS, then
// coalesced run flush (8 lanes x 8B consecutive per bucket run).
// Record: { col | (row&255)<<18 , w_bits }  (col < 2^18, rlow 8 bits).
__global__ __launch_bounds__(BIN_BLOCK) void bin_edges(
    const int* __restrict__ row, const int* __restrict__ col,
    const float* __restrict__ w,
    int* __restrict__ bcursor, int2* __restrict__ binned) {
    __shared__ int2 stage[EPB];          // 64 KB
    __shared__ int  hcnt[NBUCK];
    __shared__ int  hbase[NBUCK];
    __shared__ int  cursor[NBUCK];
    __shared__ int  lds2[BIN_BLOCK];
    int t = threadIdx.x;
    int e0 = blockIdx.x * EPB;
    int e1 = e0 + EPB; if (e1 > N_EDGES) e1 = N_EDGES;

    // A) local histogram (plain row load so chunk stays L2-hot for phase C)
    for (int i = t; i < NBUCK; i += BIN_BLOCK) hcnt[i] = 0;
    __syncthreads();
    for (int e = e0 + t; e < e1; e += BIN_BLOCK)
        atomicAdd(&hcnt[row[e] >> BUCK_SHIFT], 1);
    __syncthreads();

    // B1) global reservation
    for (int i = t; i < NBUCK; i += BIN_BLOCK) {
        int c = hcnt[i];
        hbase[i] = c ? atomicAdd(&bcursor[i], c) : 0;
    }
    // B2) local exclusive scan of hcnt -> cursor (pairs of 2 per thread)
    int i0 = 2 * t, i1 = 2 * t + 1;
    int c0 = (i0 < NBUCK) ? hcnt[i0] : 0;
    int c1 = (i1 < NBUCK) ? hcnt[i1] : 0;
    lds2[t] = c0 + c1;
    __syncthreads();
    for (int off = 1; off < BIN_BLOCK; off <<= 1) {
        int x = (t >= off) ? lds2[t - off] : 0;
        __syncthreads();
        lds2[t] += x;
        __syncthreads();
    }
    int pairExcl = lds2[t] - (c0 + c1);
    if (i0 < NBUCK) cursor[i0] = pairExcl;
    if (i1 < NBUCK) cursor[i1] = pairExcl + c0;
    __syncthreads();

    // C) stage records sorted by bucket
    for (int e = e0 + t; e < e1; e += BIN_BLOCK) {
        int r  = row[e];                 // L2-hot
        int bk = r >> BUCK_SHIFT;
        int pos = atomicAdd(&cursor[bk], 1);
        stage[pos] = make_int2(__builtin_nontemporal_load(&col[e]) | ((r & 255) << 18),
                               __float_as_int(__builtin_nontemporal_load(&w[e])));
    }
    __syncthreads();

    // D) flush runs: 8 lanes per bucket, 8 buckets per wave
    int wave = t >> 6;
    int lane = t & 63;
    int sl   = lane & 7;
    constexpr int NWAVE = BIN_BLOCK / 64;
    for (int base = wave * 8; base < NBUCK; base += NWAVE * 8) {
        int bk = base + (lane >> 3);
        if (bk < NBUCK) {
            int c  = hcnt[bk];
            int st = cursor[bk] - c;     // cursor now = local end
            int gp = hbase[bk];
            for (int j = sl; j < c; j += 8)
                binned[gp + j] = stage[st + j];
        }
    }
}

// One block per bucket. Single global read (stage raw in LDS), LDS counting
// sort by row-within-bucket, emits row_start, packs 4B records
// { col(18) | wfix14(14) }, coalesced streamout.
__global__ __launch_bounds__(256) void sort_bucket(
    const int* __restrict__ bbase, const int2* __restrict__ binned,
    unsigned* __restrict__ sorted, int* __restrict__ row_start) {
    __shared__ int2     raw[SORT_CAP];   // 48 KB
    __shared__ unsigned buf[SORT_CAP];   // 24 KB
    __shared__ int cnt[256];
    __shared__ int sc[256];
    int b = blockIdx.x, t = threadIdx.x;
    int gb = bbase[b];
    int n  = bbase[b + 1] - gb;
    int m  = n < SORT_CAP ? n : SORT_CAP;

    cnt[t] = 0;
    for (int i = t; i < m; i += 256) raw[i] = binned[gb + i];
    __syncthreads();
    for (int i = t; i < m; i += 256)
        atomicAdd(&cnt[raw[i].x >> 18], 1);
    __syncthreads();

    // exclusive scan of cnt[256]
    int v = cnt[t];
    sc[t] = v;
    __syncthreads();
    for (int off = 1; off < 256; off <<= 1) {
        int x = (t >= off) ? sc[t - off] : 0;
        __syncthreads();
        sc[t] += x;
        __syncthreads();
    }
    int excl = sc[t] - v;

    int r = (b << BUCK_SHIFT) + t;
    if (r < N_NODES) row_start[r] = gb + excl;
    if (b == NBUCK - 1 && t == 0) row_start[N_NODES] = N_EDGES;
    __syncthreads();
    cnt[t] = excl;                        // reuse as running cursor
    __syncthreads();

    for (int i = t; i < m; i += 256) {
        int2 rec = raw[i];
        int rl = rec.x >> 18;
        int k = atomicAdd(&cnt[rl], 1);
        float wv = __int_as_float(rec.y);
        unsigned q = (unsigned)(wv * 16384.f + 0.5f);
        if (q > 16383u) q = 16383u;
        buf[k] = ((unsigned)rec.x & 0x3FFFFu) | (q << 18);
    }
    __syncthreads();
    for (int i = t; i < m; i += 256)
        sorted[gb + i] = buf[i];
}

// ---------------- SpMM over a 32-dim half: 4-lane group per row, 8-deep ----------------
// Block = 64 consecutive rows (contiguous `sorted` range, mean 1024).
// Stage row_start[65] + u32 records into LDS; each 4-thread group owns one
// row (lane = 16B slot of the 64B half-row), 8-deep unconditional gather
// (tail slots -> col 0 / wt 0). src/y/y1 point at one half's table.
// LAST=false: write bf16 y half. LAST=true: out[.,half] = (a+y1+src)/3.

template<bool LAST>
__global__ __launch_bounds__(256) void spmm_half(
    const int* __restrict__ row_start, const unsigned* __restrict__ sorted,
    const uint4* __restrict__ src,     // half table: 4 x uint4 per node
    uint4* __restrict__ y,             // half table out (!LAST)
    const uint4* __restrict__ y1,      // layer-1 half table (LAST)
    float4* __restrict__ out,          // f32 final (LAST)
    int half)
{
    __shared__ unsigned erec[ECAP];
    __shared__ int rs[SROWS + 1];
    int t  = threadIdx.x;
    int R0 = blockIdx.x * SROWS;
    if (t <= SROWS) rs[t] = row_start[R0 + t];
    __syncthreads();
    int eb0 = rs[0];
    int n   = rs[SROWS] - eb0;

    int g = t >> 2;                    // row within block (0..63)
    int s = t & 3;                     // 16B slot within 64B half-row
    int r = R0 + g;
    int s0 = rs[g], s1 = rs[g + 1];
    int cnt = s1 - s0;

    float a0 = 0.f, a1 = 0.f, a2 = 0.f, a3 = 0.f;
    float a4 = 0.f, a5 = 0.f, a6 = 0.f, a7 = 0.f;
    constexpr float WSC = 1.0f / 16384.f;

#define ACC(vv, wt) \
    a0 = fmaf(wt, bfl(vv.x), a0); a1 = fmaf(wt, bfh(vv.x), a1); \
    a2 = fmaf(wt, bfl(vv.y), a2); a3 = fmaf(wt, bfh(vv.y), a3); \
    a4 = fmaf(wt, bfl(vv.z), a4); a5 = fmaf(wt, bfh(vv.z), a5); \
    a6 = fmaf(wt, bfl(vv.w), a6); a7 = fmaf(wt, bfh(vv.w), a7);

    if (n <= ECAP) {
        for (int i = t; i < n; i += 256) erec[i] = sorted[eb0 + i];
        __syncthreads();
        int lb = s0 - eb0;
        for (int k = 0; k < cnt; k += 8) {
            int   c[8]; float wv[8]; uint4 gr[8];
#pragma unroll
            for (int j = 0; j < 8; ++j) {
                int lk = k + j;
                bool v = lk < cnt;
                unsigned e = erec[lb + (v ? lk : 0)];
                c[j]  = v ? (int)(e & 0x3FFFFu) : 0;
                wv[j] = v ? (float)(e >> 18) * WSC : 0.f;
            }
#pragma unroll
            for (int j = 0; j < 8; ++j) gr[j] = src[(size_t)c[j] * 4 + s];
#pragma unroll
            for (int j = 0; j < 8; ++j) { ACC(gr[j], wv[j]) }
        }
    } else {
        // fallback: direct-global (practically never taken)
        for (int k = 0; k < cnt; k += 8) {
            int   c[8]; float wv[8]; uint4 gr[8];
#pragma unroll
            for (int j = 0; j < 8; ++j) {
                int lk = k + j;
                bool v = lk < cnt;
                unsigned e = sorted[s0 + (v ? lk : 0)];
                c[j]  = v ? (int)(e & 0x3FFFFu) : 0;
                wv[j] = v ? (float)(e >> 18) * WSC : 0.f;
            }
#pragma unroll
            for (int j = 0; j < 8; ++j) gr[j] = src[(size_t)c[j] * 4 + s];
#pragma unroll
            for (int j = 0; j < 8; ++j) { ACC(gr[j], wv[j]) }
        }
    }
#undef ACC

    if (!LAST) {
        uint4 o;
        o.x = pk(a0, a1); o.y = pk(a2, a3);
        o.z = pk(a4, a5); o.w = pk(a6, a7);
        y[(size_t)r * 4 + s] = o;
    } else {
        uint4 u1 = y1[(size_t)r * 4 + s];
        uint4 u2 = src[(size_t)r * 4 + s];
        constexpr float sc = 1.0f / 3.0f;
        float4 o0, o1;
        o0.x = (a0 + bfl(u1.x) + bfl(u2.x)) * sc;
        o0.y = (a1 + bfh(u1.x) + bfh(u2.x)) * sc;
        o0.z = (a2 + bfl(u1.y) + bfl(u2.y)) * sc;
        o0.w = (a3 + bfh(u1.y) + bfh(u2.y)) * sc;
        o1.x = (a4 + bfl(u1.z) + bfl(u2.z)) * sc;
        o1.y = (a5 + bfh(u1.z) + bfh(u2.z)) * sc;
        o1.z = (a6 + bfl(u1.w) + bfl(u2.w)) * sc;
        o1.w = (a7 + bfh(u1.w) + bfh(u2.w)) * sc;
        // out row = 16 float4; this half = 8 float4 at offset half*8
        size_t ob = (size_t)r * 16 + half * 8 + s * 2;
        out[ob]     = o0;
        out[ob + 1] = o1;
    }
}

// ---------------- launch ----------------

extern "C" void kernel_launch(void* const* d_in, const int* in_sizes, int n_in,
                              void* d_out, int out_size, void* d_ws, size_t ws_size,
                              hipStream_t stream) {
    const float* user_emb = (const float*)d_in[0];
    const float* item_emb = (const float*)d_in[1];
    const float* edge_w   = (const float*)d_in[2];
    const int*   edge_row = (const int*)d_in[3];
    const int*   edge_col = (const int*)d_in[4];

    // ws layout. binned aliases ybuf (binned dead after sort_bucket; ybuf
    // first written by spmm layer 0, which runs after).
    char* p = (char*)d_ws;
    uint4*    ebuf = (uint4*)p;     p += (size_t)N_NODES * 8 * sizeof(uint4);   // 25.6 MB
    uint4*    ybuf = (uint4*)p;     p += (size_t)N_NODES * 8 * sizeof(uint4);   // 25.6 MB
    unsigned* sorted = (unsigned*)p; p += (size_t)N_EDGES * sizeof(unsigned);   // 12.8 MB
    int*   bcnt = (int*)p;          p += (size_t)NBUCK * sizeof(int);
    int*   bbase = (int*)p;         p += (size_t)(NBUCK + 1) * sizeof(int);
    int*   bcursor = (int*)p;       p += (size_t)NBUCK * sizeof(int);
    int*   row_start = (int*)p;     p += (size_t)(N_NODES + 1) * sizeof(int);
    int2*  binned = (int2*)ybuf;    // alias

    hipMemsetAsync(bcnt, 0, (size_t)NBUCK * sizeof(int), stream);

    // fused: coarse histogram (blocks 0..511) + concat->bf16 half-layout
    prep<<<HIST_BLOCKS + CONCAT_BLOCKS, 256, 0, stream>>>(
        edge_row, bcnt, (const float4*)user_emb, (const float4*)item_emb, ebuf);

    scan_buckets<<<1, 1024, 0, stream>>>(bcnt, bbase, bcursor);
    bin_edges<<<NBIN_BLOCKS, BIN_BLOCK, 0, stream>>>(edge_row, edge_col, edge_w,
                                                     bcursor, binned);
    sort_bucket<<<NBUCK, 256, 0, stream>>>(bbase, binned, sorted, row_start);

    uint4* e0 = ebuf;
    uint4* e1 = ebuf + (size_t)N_NODES * 4;
    uint4* y0 = ybuf;
    uint4* y1p = ybuf + (size_t)N_NODES * 4;
    float4* out = (float4*)d_out;
    int grid = N_NODES / SROWS;                    // 3125 blocks, 64 rows each

    // half 0 chain: table stays 12.8MB-hot across layers
    spmm_half<false><<<grid, 256, 0, stream>>>(row_start, sorted, e0, y0, nullptr, nullptr, 0);
    spmm_half<false><<<grid, 256, 0, stream>>>(row_start, sorted, y0, e0, nullptr, nullptr, 0);
    spmm_half<true ><<<grid, 256, 0, stream>>>(row_start, sorted, e0, nullptr, y0, out, 0);
    // half 1 chain
    spmm_half<false><<<grid, 256, 0, stream>>>(row_start, sorted, e1, y1p, nullptr, nullptr, 1);
    spmm_half<false><<<grid, 256, 0, stream>>>(row_start, sorted, y1p, e1, nullptr, nullptr, 1);
    spmm_half<true ><<<grid, 256, 0, stream>>>(row_start, sorted, e1, nullptr, y1p, out, 1);
}

// Round 9
// 392.881 us; speedup vs baseline: 1.2658x; 1.2658x over previous
//
#include <hip/hip_runtime.h>
#include <hip/hip_bf16.h>

// LightGCN: 3 layers of SpMM on 200000x64 embeddings, 3.2M edges.
// R13: revert R12's dim-split (halved gather rows to 64B < 128B line ->
//      2x miss over-fetch + 2x record decode; spmm 71us/layer -> ~100).
//      KEEP the proven-safe 4B record quantization (R12 passed, absmax
//      unchanged) and extend it upstream: bin_edges stages/writes split
//      4B col|wq + 1B rlow arrays (LDS 64->40KB -> 3 blocks/CU, writes
//      26->16MB; it was occupancy/latency-bound: VALU 5%, occ 22%);
//      sort_bucket consumes them (LDS 74->56KB) and writes 4B sorted
//      (25.6->12.8MB). spmm = R10 structure with u32 records (sorted
//      stream halves per layer).
// R10: spmm LDS record staging + 8-deep gather MLP, 8-lane group/row.
// R9:  bin_edges block-local counting sort + coalesced run flush.
// R7:  no f32 acc RMW (layer2 fuses out=(a+y1+y2)/3).
// R5:  two-level counting-sort CSR build.

constexpr int NUM_USERS = 100000;
constexpr int NUM_ITEMS = 100000;
constexpr int N_NODES   = NUM_USERS + NUM_ITEMS;   // 200000
constexpr int EMB       = 64;
constexpr int N_EDGES   = 3200000;

constexpr int BUCK_SHIFT = 8;                       // 256 rows per bucket
constexpr int NBUCK = (N_NODES + 255) >> BUCK_SHIFT; // 782
constexpr int BIN_BLOCK = 512;
constexpr int EPB = 8192;                            // edges per bin block
constexpr int NBIN_BLOCKS = (N_EDGES + EPB - 1) / EPB; // 391
constexpr int SORT_CAP = 6144;                       // mean 4096, sigma 64

constexpr int HIST_BLOCKS   = 512;
constexpr int CONCAT_BLOCKS = (N_NODES * 8 + 255) / 256; // 6250

constexpr int ROWS_PER_BLOCK = 32;                   // spmm
constexpr int ECAP = 1536;                           // LDS record cap (mean 512)

// ---------------- bf16 helpers ----------------

__device__ __forceinline__ float bfl(unsigned u) { return __uint_as_float(u << 16); }
__device__ __forceinline__ float bfh(unsigned u) { return __uint_as_float(u & 0xFFFF0000u); }
__device__ __forceinline__ unsigned f2bf(float f) {          // RNE
    unsigned u = __float_as_uint(f);
    return (u + 0x7FFFu + ((u >> 16) & 1u)) >> 16;
}
__device__ __forceinline__ unsigned pk(float lo, float hi) {
    return f2bf(lo) | (f2bf(hi) << 16);
}

// ---------------- prep: coarse histogram + concat->bf16 (fused, independent) ----------------

__global__ __launch_bounds__(256) void prep(
    const int* __restrict__ row, int* __restrict__ bcnt,
    const float4* __restrict__ u, const float4* __restrict__ it,
    uint4* __restrict__ ebuf) {
    __shared__ int h[NBUCK];
    if (blockIdx.x < HIST_BLOCKS) {
        for (int i = threadIdx.x; i < NBUCK; i += 256) h[i] = 0;
        __syncthreads();
        int nt = HIST_BLOCKS * 256;
        for (int e = blockIdx.x * 256 + threadIdx.x; e < N_EDGES; e += nt) {
            int r = __builtin_nontemporal_load(&row[e]);
            atomicAdd(&h[r >> BUCK_SHIFT], 1);
        }
        __syncthreads();
        for (int i = threadIdx.x; i < NBUCK; i += 256) {
            int c = h[i];
            if (c) atomicAdd(&bcnt[i], c);
        }
    } else {
        int i = (blockIdx.x - HIST_BLOCKS) * 256 + threadIdx.x;
        if (i >= N_NODES * 8) return;
        const float4* s = (i < NUM_USERS * 8) ? (u + 2 * (size_t)i)
                                              : (it + 2 * ((size_t)i - (size_t)NUM_USERS * 8));
        float4 f0 = s[0], f1 = s[1];
        uint4 o;
        o.x = pk(f0.x, f0.y); o.y = pk(f0.z, f0.w);
        o.z = pk(f1.x, f1.y); o.w = pk(f1.z, f1.w);
        ebuf[i] = o;
    }
}

// ---------------- CSR build: two-level counting sort ----------------

// Exclusive scan of 782 bucket counts -> bucket bases + cursors.
__global__ __launch_bounds__(1024) void scan_buckets(const int* __restrict__ bcnt,
                                                     int* __restrict__ bbase,
                                                     int* __restrict__ bcursor) {
    __shared__ int lds[1024];
    int t = threadIdx.x;
    int v = (t < NBUCK) ? bcnt[t] : 0;
    lds[t] = v;
    __syncthreads();
    for (int off = 1; off < 1024; off <<= 1) {
        int x = (t >= off) ? lds[t - off] : 0;
        __syncthreads();
        lds[t] += x;
        __syncthreads();
    }
    int excl = lds[t] - v;
    if (t < NBUCK) { bbase[t] = excl; bcursor[t] = excl; }
    if (t == 0) bbase[NBUCK] = N_EDGES;
}

// Bin edges into coarse buckets, block-local counting sort in LDS, then
// coalesced run flush. Split staging: 4B {col(18)|wq14<<18} + 1B rlow.
__global__ __launch_bounds__(BIN_BLOCK) void bin_edges(
    const int* __restrict__ row, const int* __restrict__ col,
    const float* __restrict__ w,
    int* __restrict__ bcursor,
    unsigned* __restrict__ binned_cw, unsigned char* __restrict__ binned_rl) {
    __shared__ unsigned      stage_cw[EPB];   // 32 KB
    __shared__ unsigned char stage_rl[EPB];   // 8 KB
    __shared__ int  hcnt[NBUCK];
    __shared__ int  hbase[NBUCK];
    __shared__ int  cursor[NBUCK];
    __shared__ int  lds2[BIN_BLOCK];
    int t = threadIdx.x;
    int e0 = blockIdx.x * EPB;
    int e1 = e0 + EPB; if (e1 > N_EDGES) e1 = N_EDGES;

    // A) local histogram (plain row load so chunk stays L2-hot for phase C)
    for (int i = t; i < NBUCK; i += BIN_BLOCK) hcnt[i] = 0;
    __syncthreads();
    for (int e = e0 + t; e < e1; e += BIN_BLOCK)
        atomicAdd(&hcnt[row[e] >> BUCK_SHIFT], 1);
    __syncthreads();

    // B1) global reservation
    for (int i = t; i < NBUCK; i += BIN_BLOCK) {
        int c = hcnt[i];
        hbase[i] = c ? atomicAdd(&bcursor[i], c) : 0;
    }
    // B2) local exclusive scan of hcnt -> cursor (pairs of 2 per thread)
    int i0 = 2 * t, i1 = 2 * t + 1;
    int c0 = (i0 < NBUCK) ? hcnt[i0] : 0;
    int c1 = (i1 < NBUCK) ? hcnt[i1] : 0;
    lds2[t] = c0 + c1;
    __syncthreads();
    for (int off = 1; off < BIN_BLOCK; off <<= 1) {
        int x = (t >= off) ? lds2[t - off] : 0;
        __syncthreads();
        lds2[t] += x;
        __syncthreads();
    }
    int pairExcl = lds2[t] - (c0 + c1);
    if (i0 < NBUCK) cursor[i0] = pairExcl;
    if (i1 < NBUCK) cursor[i1] = pairExcl + c0;
    __syncthreads();

    // C) stage records sorted by bucket (quantize w here: 14-bit fixed,
    //    abs err 3e-5 -- proven negligible vs bf16 feed, R12 passed)
    for (int e = e0 + t; e < e1; e += BIN_BLOCK) {
        int r  = row[e];                 // L2-hot
        int bk = r >> BUCK_SHIFT;
        int pos = atomicAdd(&cursor[bk], 1);
        float wv = __builtin_nontemporal_load(&w[e]);
        unsigned q = (unsigned)(wv * 16384.f + 0.5f);
        if (q > 16383u) q = 16383u;
        stage_cw[pos] = (unsigned)__builtin_nontemporal_load(&col[e]) | (q << 18);
        stage_rl[pos] = (unsigned char)(r & 255);
    }
    __syncthreads();

    // D) flush runs: 8 lanes per bucket, 8 buckets per wave
    int wave = t >> 6;
    int lane = t & 63;
    int sl   = lane & 7;
    constexpr int NWAVE = BIN_BLOCK / 64;
    for (int base = wave * 8; base < NBUCK; base += NWAVE * 8) {
        int bk = base + (lane >> 3);
        if (bk < NBUCK) {
            int c  = hcnt[bk];
            int st = cursor[bk] - c;     // cursor now = local end
            int gp = hbase[bk];
            for (int j = sl; j < c; j += 8) {
                binned_cw[gp + j] = stage_cw[st + j];
                binned_rl[gp + j] = stage_rl[st + j];
            }
        }
    }
}

// One block per bucket. Single global read (stage raw in LDS), LDS counting
// sort by rlow, emits row_start, streams out 4B records {col(18)|wq14}.
__global__ __launch_bounds__(256) void sort_bucket(
    const int* __restrict__ bbase,
    const unsigned* __restrict__ binned_cw, const unsigned char* __restrict__ binned_rl,
    unsigned* __restrict__ sorted, int* __restrict__ row_start) {
    __shared__ unsigned      raw_cw[SORT_CAP];  // 24 KB
    __shared__ unsigned char raw_rl[SORT_CAP];  // 6 KB
    __shared__ unsigned      buf[SORT_CAP];     // 24 KB
    __shared__ int cnt[256];
    __shared__ int sc[256];
    int b = blockIdx.x, t = threadIdx.x;
    int gb = bbase[b];
    int n  = bbase[b + 1] - gb;
    int m  = n < SORT_CAP ? n : SORT_CAP;

    cnt[t] = 0;
    for (int i = t; i < m; i += 256) {
        raw_cw[i] = binned_cw[gb + i];
        raw_rl[i] = binned_rl[gb + i];
    }
    __syncthreads();
    for (int i = t; i < m; i += 256)
        atomicAdd(&cnt[raw_rl[i]], 1);
    __syncthreads();

    // exclusive scan of cnt[256]
    int v = cnt[t];
    sc[t] = v;
    __syncthreads();
    for (int off = 1; off < 256; off <<= 1) {
        int x = (t >= off) ? sc[t - off] : 0;
        __syncthreads();
        sc[t] += x;
        __syncthreads();
    }
    int excl = sc[t] - v;

    int r = (b << BUCK_SHIFT) + t;
    if (r < N_NODES) row_start[r] = gb + excl;
    if (b == NBUCK - 1 && t == 0) row_start[N_NODES] = N_EDGES;
    __syncthreads();
    cnt[t] = excl;                        // reuse as running cursor
    __syncthreads();

    for (int i = t; i < m; i += 256) {
        int k = atomicAdd(&cnt[raw_rl[i]], 1);
        buf[k] = raw_cw[i];
    }
    __syncthreads();
    for (int i = t; i < m; i += 256)
        sorted[gb + i] = buf[i];
}

// ---------------- SpMM: LDS-staged u32 records, 8-lane group per row, 8-deep ----------------
// Block = 32 consecutive rows; their records are a contiguous `sorted`
// range (mean 512). Stage row_start[33] + records into LDS coalesced;
// each 8-thread group owns one row (lane = 16B slot of the 128B row),
// 8-deep unconditional gather loop (tail slots -> col 0 / wt 0).
// LAST=false: write bf16 y. LAST=true: out = (a + y1[r] + src[r]) / 3.

template<bool LAST>
__global__ __launch_bounds__(256) void spmm_bf16(
    const int* __restrict__ row_start, const unsigned* __restrict__ sorted,
    const uint4* __restrict__ src,     // bf16 rows: 8 x uint4 per row
    uint4* __restrict__ y,             // bf16 rows out (!LAST)
    const uint4* __restrict__ y1,      // layer-1 output rows (LAST)
    float4* __restrict__ out)          // f32 final (LAST)
{
    __shared__ unsigned erec[ECAP];    // 6 KB
    __shared__ int rs[ROWS_PER_BLOCK + 1];
    int t  = threadIdx.x;
    int R0 = blockIdx.x * ROWS_PER_BLOCK;
    if (t <= ROWS_PER_BLOCK) rs[t] = row_start[R0 + t];
    __syncthreads();
    int eb0 = rs[0];
    int n   = rs[ROWS_PER_BLOCK] - eb0;

    int g = t >> 3;                    // row within block (0..31)
    int s = t & 7;                     // 16B slot within row
    int r = R0 + g;
    int s0 = rs[g], s1 = rs[g + 1];
    int cnt = s1 - s0;

    float a0 = 0.f, a1 = 0.f, a2 = 0.f, a3 = 0.f;
    float a4 = 0.f, a5 = 0.f, a6 = 0.f, a7 = 0.f;
    constexpr float WSC = 1.0f / 16384.f;

#define ACC(vv, wt) \
    a0 = fmaf(wt, bfl(vv.x), a0); a1 = fmaf(wt, bfh(vv.x), a1); \
    a2 = fmaf(wt, bfl(vv.y), a2); a3 = fmaf(wt, bfh(vv.y), a3); \
    a4 = fmaf(wt, bfl(vv.z), a4); a5 = fmaf(wt, bfh(vv.z), a5); \
    a6 = fmaf(wt, bfl(vv.w), a6); a7 = fmaf(wt, bfh(vv.w), a7);

    if (n <= ECAP) {
        // stage the block's contiguous record range (each record once)
        for (int i = t; i < n; i += 256) erec[i] = sorted[eb0 + i];
        __syncthreads();
        int lb = s0 - eb0;
        for (int k = 0; k < cnt; k += 8) {
            int   c[8]; float wv[8]; uint4 gr[8];
#pragma unroll
            for (int j = 0; j < 8; ++j) {
                int lk = k + j;
                bool v = lk < cnt;
                unsigned e = erec[lb + (v ? lk : 0)];
                c[j]  = v ? (int)(e & 0x3FFFFu) : 0;
                wv[j] = v ? (float)(e >> 18) * WSC : 0.f;
            }
#pragma unroll
            for (int j = 0; j < 8; ++j) gr[j] = src[(size_t)c[j] * 8 + s];
#pragma unroll
            for (int j = 0; j < 8; ++j) { ACC(gr[j], wv[j]) }
        }
    } else {
        // fallback: direct-global 8-deep (practically never taken)
        for (int k = 0; k < cnt; k += 8) {
            int   c[8]; float wv[8]; uint4 gr[8];
#pragma unroll
            for (int j = 0; j < 8; ++j) {
                int lk = k + j;
                bool v = lk < cnt;
                unsigned e = sorted[s0 + (v ? lk : 0)];
                c[j]  = v ? (int)(e & 0x3FFFFu) : 0;
                wv[j] = v ? (float)(e >> 18) * WSC : 0.f;
            }
#pragma unroll
            for (int j = 0; j < 8; ++j) gr[j] = src[(size_t)c[j] * 8 + s];
#pragma unroll
            for (int j = 0; j < 8; ++j) { ACC(gr[j], wv[j]) }
        }
    }
#undef ACC

    if (!LAST) {
        uint4 o;
        o.x = pk(a0, a1); o.y = pk(a2, a3);
        o.z = pk(a4, a5); o.w = pk(a6, a7);
        y[(size_t)r * 8 + s] = o;
    } else {
        // read the two earlier layer outputs for this row (read-once)
        uint4 u1 = y1[(size_t)r * 8 + s];
        uint4 u2 = src[(size_t)r * 8 + s];
        constexpr float sc = 1.0f / 3.0f;
        float4 o0, o1;
        o0.x = (a0 + bfl(u1.x) + bfl(u2.x)) * sc;
        o0.y = (a1 + bfh(u1.x) + bfh(u2.x)) * sc;
        o0.z = (a2 + bfl(u1.y) + bfl(u2.y)) * sc;
        o0.w = (a3 + bfh(u1.y) + bfh(u2.y)) * sc;
        o1.x = (a4 + bfl(u1.z) + bfl(u2.z)) * sc;
        o1.y = (a5 + bfh(u1.z) + bfh(u2.z)) * sc;
        o1.z = (a6 + bfl(u1.w) + bfl(u2.w)) * sc;
        o1.w = (a7 + bfh(u1.w) + bfh(u2.w)) * sc;
        size_t ob = (size_t)r * 16 + 2 * s;
        out[ob]     = o0;
        out[ob + 1] = o1;
    }
}

// ---------------- launch ----------------

extern "C" void kernel_launch(void* const* d_in, const int* in_sizes, int n_in,
                              void* d_out, int out_size, void* d_ws, size_t ws_size,
                              hipStream_t stream) {
    const float* user_emb = (const float*)d_in[0];
    const float* item_emb = (const float*)d_in[1];
    const float* edge_w   = (const float*)d_in[2];
    const int*   edge_row = (const int*)d_in[3];
    const int*   edge_col = (const int*)d_in[4];

    // ws layout. binned_* alias ybuf (dead after sort_bucket; ybuf first
    // written by spmm layer 0, which runs after).
    char* p = (char*)d_ws;
    uint4*    ebuf = (uint4*)p;      p += (size_t)N_NODES * 8 * sizeof(uint4);  // 25.6 MB
    uint4*    ybuf = (uint4*)p;      p += (size_t)N_NODES * 8 * sizeof(uint4);  // 25.6 MB
    unsigned* sorted = (unsigned*)p; p += (size_t)N_EDGES * sizeof(unsigned);   // 12.8 MB
    int*   bcnt = (int*)p;           p += (size_t)NBUCK * sizeof(int);
    int*   bbase = (int*)p;          p += (size_t)(NBUCK + 1) * sizeof(int);
    int*   bcursor = (int*)p;        p += (size_t)NBUCK * sizeof(int);
    int*   row_start = (int*)p;      p += (size_t)(N_NODES + 1) * sizeof(int);
    unsigned*      binned_cw = (unsigned*)ybuf;                    // 12.8 MB alias
    unsigned char* binned_rl = (unsigned char*)(ybuf) + (size_t)N_EDGES * 4; // 3.2 MB alias

    hipMemsetAsync(bcnt, 0, (size_t)NBUCK * sizeof(int), stream);

    // fused: coarse histogram (blocks 0..511) + concat->bf16 (rest)
    prep<<<HIST_BLOCKS + CONCAT_BLOCKS, 256, 0, stream>>>(
        edge_row, bcnt, (const float4*)user_emb, (const float4*)item_emb, ebuf);

    scan_buckets<<<1, 1024, 0, stream>>>(bcnt, bbase, bcursor);
    bin_edges<<<NBIN_BLOCKS, BIN_BLOCK, 0, stream>>>(edge_row, edge_col, edge_w,
                                                     bcursor, binned_cw, binned_rl);
    sort_bucket<<<NBUCK, 256, 0, stream>>>(bbase, binned_cw, binned_rl,
                                           sorted, row_start);

    int grid = N_NODES / ROWS_PER_BLOCK;           // 6250 blocks, 32 rows each
    // layer 0: ebuf -> ybuf (y1)
    spmm_bf16<false><<<grid, 256, 0, stream>>>(row_start, sorted, ebuf, ybuf,
                                               nullptr, nullptr);
    // layer 1: ybuf -> ebuf (y2; ebuf dead after layer 0)
    spmm_bf16<false><<<grid, 256, 0, stream>>>(row_start, sorted, ybuf, ebuf,
                                               nullptr, nullptr);
    // layer 2: src=ebuf (y2), epilogue reads ybuf (y1) + ebuf rows, writes out
    spmm_bf16<true><<<grid, 256, 0, stream>>>(row_start, sorted, ebuf, nullptr,
                                              ybuf, (float4*)d_out);
}